// Round 5
// baseline (1267.706 us; speedup 1.0000x reference)
//
#include <hip/hip_runtime.h>
#include <hip/hip_bf16.h>

typedef __hip_bfloat16 bf16;
typedef __attribute__((ext_vector_type(8))) short s8v;
typedef __attribute__((ext_vector_type(4))) float f32x4;

#define NN 4096
#define FDIM 16
#define BATCH 4
#define TSTEPS 12

static __device__ __forceinline__ short f2bf(float f) {
  bf16 h = __float2bfloat16(f);
  return *reinterpret_cast<short*>(&h);
}

// ---------------- adj (f32) -> bf16 copy ----------------
__global__ __launch_bounds__(256) void adj_to_bf16(const float* __restrict__ adjF,
                                                   short* __restrict__ adjB)
{
  size_t i = ((size_t)blockIdx.x * 256 + threadIdx.x) * 8;
  f32x4 u0 = *(const f32x4*)(adjF + i);
  f32x4 u1 = *(const f32x4*)(adjF + i + 4);
  s8v v;
#pragma unroll
  for (int j = 0; j < 4; j++) { v[j] = f2bf(u0[j]); v[4 + j] = f2bf(u1[j]); }
  *(s8v*)(adjB + i) = v;
}

// ---------------- wave-autonomous adjacency GEMM ----------------
// out[ks][row][outld] partial = adj[row, ks*KC : (ks+1)*KC] @ Z[k, col]
// Each wave: 16-row x 64-col tile, fragments loaded straight from global.
// No LDS, no barriers -> deep vmcnt pipelining; occupancy via block count.
template<int KC>
__global__ __launch_bounds__(256) void gemm_wv(
    const short* __restrict__ adjB,  // [4096][4096] bf16 bits
    const short* __restrict__ zt,    // [cols][4096] bf16 bits (B^T layout)
    float* __restrict__ out, int outld)
{
  const int lane = threadIdx.x & 63;
  const int wid  = threadIdx.x >> 6;
  const int r16  = lane & 15, g = lane >> 4;
  const int rowBase = blockIdx.x * 64 + wid * 16;
  const int colBase = blockIdx.y * 64;
  const size_t k0 = (size_t)blockIdx.z * KC;

  // A-frag: lane holds A[row=r16][k = g*8 + j]; B-frag: B[k=g*8+j][col=r16]
  const short* aP = adjB + (size_t)(rowBase + r16) * NN + k0 + g * 8;
  const short* bP = zt   + (size_t)(colBase + r16) * NN + k0 + g * 8;

  f32x4 acc[4];
#pragma unroll
  for (int i = 0; i < 4; i++) acc[i] = (f32x4){0.f, 0.f, 0.f, 0.f};

#pragma unroll 4
  for (int kt = 0; kt < KC; kt += 64) {
    s8v a0 = *(const s8v*)(aP + kt);
    s8v a1 = *(const s8v*)(aP + kt + 32);
    s8v b0[4], b1[4];
#pragma unroll
    for (int gg = 0; gg < 4; gg++) {
      b0[gg] = *(const s8v*)(bP + (size_t)gg * 16 * NN + kt);
      b1[gg] = *(const s8v*)(bP + (size_t)gg * 16 * NN + kt + 32);
    }
#pragma unroll
    for (int gg = 0; gg < 4; gg++)
      acc[gg] = __builtin_amdgcn_mfma_f32_16x16x32_bf16(a0, b0[gg], acc[gg], 0, 0, 0);
#pragma unroll
    for (int gg = 0; gg < 4; gg++)
      acc[gg] = __builtin_amdgcn_mfma_f32_16x16x32_bf16(a1, b1[gg], acc[gg], 0, 0, 0);
  }

  // C/D layout (m89): col = lane&15, row = (lane>>4)*4 + j
  float* o = out + ((size_t)blockIdx.z * NN + rowBase + g * 4) * outld + colBase + r16;
#pragma unroll
  for (int gg = 0; gg < 4; gg++)
#pragma unroll
    for (int j = 0; j < 4; j++)
      o[(size_t)j * outld + gg * 16] = acc[gg][j];
}

// ---------------- pack x (f32) into X^T bf16: XT[(b*T+t)*16+f][n] ----------------
__global__ __launch_bounds__(256) void pack_x(const float* __restrict__ x, short* __restrict__ XT)
{
  int idx = blockIdx.x * 256 + threadIdx.x;   // r*4096+n, r=b*T+t
  int r = idx >> 12, n = idx & 4095;
  const float* xp = x + ((size_t)r * NN + n) * FDIM;
#pragma unroll
  for (int q = 0; q < 4; q++) {
    f32x4 u = *(const f32x4*)(xp + q * 4);
#pragma unroll
    for (int j = 0; j < 4; j++)
      XT[(size_t)(r * 16 + q * 4 + j) * NN + n] = f2bf(u[j]);
  }
}

// ---------------- init h=c=m=1 ----------------
__global__ __launch_bounds__(256) void init_state(float* c_st, float* m_st, short* ztA, short* ztB)
{
  int idx = blockIdx.x * 256 + threadIdx.x;   // 0..262143
  int cc = idx >> 12, n = idx & 4095;
  int b = cc >> 4, f = cc & 15;
  short one = f2bf(1.0f);
  ztA[(size_t)cc * NN + n] = one;                        // h0 rows b*16+f
  ztB[(size_t)(b * 32 + 16 + f) * NN + n] = one;         // m0 slot
  c_st[(size_t)(b * NN + n) * FDIM + f] = 1.0f;
  m_st[(size_t)(b * NN + n) * FDIM + f] = 1.0f;
}

// ---------------- step A: gates + LSTM cell update ----------------
// block = 256 threads handles 16 (b,n) pairs; phase1 stages split-K reduction
// into LDS (thread=(pair,q)), phase2 computes gates (thread=(pair,f)).
__global__ __launch_bounds__(256) void step_a(
    const float* __restrict__ P,    // [16][4096][64]  (adj@h split-K partials)
    const float* __restrict__ AX,   // [4096][768]     (adj@x, all t)
    const float* __restrict__ Wx, const float* __restrict__ bx,
    const float* __restrict__ Wh, const float* __restrict__ bh,
    float* __restrict__ c_st,
    short* __restrict__ ztB,        // write h_mid into rows b*32+f
    int t)
{
  __shared__ float wx[16][64], wh[16][64], bxs[64], bhs[64];
  __shared__ float azxS[16][16], azhS[16][16];
  int tid = threadIdx.x;
#pragma unroll
  for (int i = 0; i < 4; i++) {
    int c = tid + i * 256;
    wx[c >> 6][c & 63] = Wx[c];
    wh[c >> 6][c & 63] = Wh[c];
  }
  if (tid < 64) { bxs[tid] = bx[tid]; bhs[tid] = bh[tid]; }

  int p = tid >> 4, q = tid & 15;
  int pg = blockIdx.x * 16 + p;               // 0..16383 = b*4096+n
  int b = pg >> 12, n = pg & 4095;

  float s = 0.f;
#pragma unroll
  for (int ks = 0; ks < 16; ks++) s += P[(size_t)ks * (NN * 64) + (size_t)n * 64 + b * 16 + q];
  azhS[p][q] = s;
  azxS[p][q] = AX[(size_t)n * 768 + (b * TSTEPS + t) * 16 + q];
  __syncthreads();

  int f = q;
  float azx[16], azh[16];
#pragma unroll
  for (int qq = 0; qq < 16; qq++) { azx[qq] = azxS[p][qq]; azh[qq] = azhS[p][qq]; }

  float fx = bxs[f], ix = bxs[16 + f], cx = bxs[32 + f], ox = bxs[48 + f];
  float fh = bhs[f], ih = bhs[16 + f], ch = bhs[32 + f], oh = bhs[48 + f];
#pragma unroll
  for (int qq = 0; qq < 16; qq++) {
    fx += azx[qq] * wx[qq][f];      ix += azx[qq] * wx[qq][16 + f];
    cx += azx[qq] * wx[qq][32 + f]; ox += azx[qq] * wx[qq][48 + f];
    fh += azh[qq] * wh[qq][f];      ih += azh[qq] * wh[qq][16 + f];
    ch += azh[qq] * wh[qq][32 + f]; oh += azh[qq] * wh[qq][48 + f];
  }
  fx = fmaxf(fx, 0.f); ix = fmaxf(ix, 0.f); cx = fmaxf(cx, 0.f); ox = fmaxf(ox, 0.f);
  fh = fmaxf(fh, 0.f); ih = fmaxf(ih, 0.f); ch = fmaxf(ch, 0.f); oh = fmaxf(oh, 0.f);
  float fg = 1.f / (1.f + __expf(-(fx + fh)));
  float ig = 1.f / (1.f + __expf(-(ix + ih)));
  float og = 1.f / (1.f + __expf(-(ox + oh)));
  float cn = fg * c_st[(size_t)pg * 16 + f] + ig * tanhf(cx + ch);
  float hm = og * tanhf(cn);
  c_st[(size_t)pg * 16 + f] = cn;
  ztB[(size_t)(b * 32 + f) * NN + n] = f2bf(hm);
}

// ---------------- step B: self-attention memory stage ----------------
__global__ __launch_bounds__(256) void step_b(
    const float* __restrict__ P,    // [8][4096][128] (adj@[h_mid|m] partials)
    const float* __restrict__ Wsh, const float* __restrict__ bsh,
    const float* __restrict__ Wsm, const float* __restrict__ bsm,
    float* __restrict__ m_st, float* __restrict__ h_st,
    short* __restrict__ ztA, short* __restrict__ ztB,
    float* __restrict__ outH, int t)
{
  __shared__ float wsh[16][48], wsm[16][48], bshs[48], bsms[48];
  __shared__ float ahS[16][16], amS[16][16];
  int tid = threadIdx.x;
#pragma unroll
  for (int i = 0; i < 3; i++) {
    int c = tid + i * 256;
    wsh[c / 48][c % 48] = Wsh[c];
    wsm[c / 48][c % 48] = Wsm[c];
  }
  if (tid < 48) { bshs[tid] = bsh[tid]; bsms[tid] = bsm[tid]; }

  int p = tid >> 4, q = tid & 15;
  int pg = blockIdx.x * 16 + p;               // b*4096+n
  int b = pg >> 12, n = pg & 4095;

  float s0 = 0.f, s1 = 0.f;
#pragma unroll
  for (int ks = 0; ks < 8; ks++) {
    const float* pp = P + (size_t)ks * (NN * 128) + (size_t)n * 128 + b * 32;
    s0 += pp[q];
    s1 += pp[16 + q];
  }
  ahS[p][q] = s0;
  amS[p][q] = s1;
  __syncthreads();

  int f = q;
  float ah[16], am[16];
#pragma unroll
  for (int qq = 0; qq < 16; qq++) { ah[qq] = ahS[p][qq]; am[qq] = amS[p][qq]; }

  float ih_ = bshs[f], gh_ = bshs[16 + f], oh_ = bshs[32 + f];
  float im_ = bsms[f], gm_ = bsms[16 + f], om_ = bsms[32 + f];
#pragma unroll
  for (int qq = 0; qq < 16; qq++) {
    ih_ += ah[qq] * wsh[qq][f];  gh_ += ah[qq] * wsh[qq][16 + f];  oh_ += ah[qq] * wsh[qq][32 + f];
    im_ += am[qq] * wsm[qq][f];  gm_ += am[qq] * wsm[qq][16 + f];  om_ += am[qq] * wsm[qq][32 + f];
  }
  ih_ = fmaxf(ih_, 0.f); gh_ = fmaxf(gh_, 0.f); oh_ = fmaxf(oh_, 0.f);
  im_ = fmaxf(im_, 0.f); gm_ = fmaxf(gm_, 0.f); om_ = fmaxf(om_, 0.f);
  float i2 = 1.f / (1.f + __expf(-(ih_ + im_)));
  float g2 = 1.f / (1.f + __expf(-(gh_ + gm_)));
  float o2 = 1.f / (1.f + __expf(-(oh_ + om_)));
  float mo = m_st[(size_t)pg * 16 + f];
  float mn = i2 * mo + (1.f - i2) * g2;
  float hn = mn * o2;
  m_st[(size_t)pg * 16 + f] = mn;
  h_st[(size_t)pg * 16 + f] = hn;
  ztA[(size_t)(b * 16 + f) * NN + n] = f2bf(hn);
  ztB[(size_t)(b * 32 + 16 + f) * NN + n] = f2bf(mn);
  outH[((size_t)(b * TSTEPS + t) * NN + n) * FDIM + f] = hn;
}

// ---------------- final: last_h, last_c, last_m (f32 out) ----------------
__global__ __launch_bounds__(256) void finalize(
    const float* __restrict__ h_st, const float* __restrict__ c_st,
    const float* __restrict__ m_st, float* __restrict__ out)
{
  int idx = blockIdx.x * 256 + threadIdx.x;   // 0..262143
  size_t base = (size_t)BATCH * TSTEPS * NN * FDIM;
  out[base + idx]          = h_st[idx];
  out[base + 262144 + idx] = c_st[idx];
  out[base + 524288 + idx] = m_st[idx];
}

extern "C" void kernel_launch(void* const* d_in, const int* in_sizes, int n_in,
                              void* d_out, int out_size, void* d_ws, size_t ws_size,
                              hipStream_t stream)
{
  const float* x    = (const float*)d_in[0];
  const float* adjF = (const float*)d_in[1];
  const float* Wx   = (const float*)d_in[2];
  const float* bx   = (const float*)d_in[3];
  const float* Wh   = (const float*)d_in[4];
  const float* bh   = (const float*)d_in[5];
  const float* Wsh  = (const float*)d_in[6];
  const float* bsh  = (const float*)d_in[7];
  const float* Wsm  = (const float*)d_in[8];
  const float* bsm  = (const float*)d_in[9];
  float* out = (float*)d_out;

  char* ws = (char*)d_ws;
  float* AX   = (float*)ws;                    // 4096*768*4    = 12,582,912
  float* P    = (float*)(ws + 12582912);       // 16*4096*64*4  = 16,777,216 (also 8*4096*128*4)
  short* XT   = (short*)(ws + 29360128);       // 768*4096*2    =  6,291,456
  short* ztA  = (short*)(ws + 35651584);       // 64*4096*2     =    524,288
  short* ztB  = (short*)(ws + 36175872);       // 128*4096*2    =  1,048,576
  float* c_st = (float*)(ws + 37224448);       // 1,048,576 each
  float* m_st = (float*)(ws + 38273024);
  float* h_st = (float*)(ws + 39321600);
  short* adjB = (short*)(ws + 40370176);       // 4096*4096*2   = 33,554,432

  init_state<<<1024, 256, 0, stream>>>(c_st, m_st, ztA, ztB);
  pack_x<<<768, 256, 0, stream>>>(x, XT);
  adj_to_bf16<<<8192, 256, 0, stream>>>(adjF, adjB);

  // adj @ x for all (b,t): 768 cols, 12 col-tiles, no split-K
  gemm_wv<4096><<<dim3(64, 12, 1), 256, 0, stream>>>(adjB, XT, AX, 768);

  for (int t = 0; t < TSTEPS; t++) {
    // adj @ h : 64 cols, split-K=16 -> 1024 blocks (4/CU)
    gemm_wv<256><<<dim3(64, 1, 16), 256, 0, stream>>>(adjB, ztA, P, 64);
    step_a<<<1024, 256, 0, stream>>>(P, AX, Wx, bx, Wh, bh, c_st, ztB, t);
    // adj @ [h_mid | m] : 128 cols, 2 col-tiles x split-K=8 -> 1024 blocks
    gemm_wv<512><<<dim3(64, 2, 8), 256, 0, stream>>>(adjB, ztB, P, 128);
    step_b<<<1024, 256, 0, stream>>>(P, Wsh, bsh, Wsm, bsm, m_st, h_st, ztA, ztB, out, t);
  }
  finalize<<<1024, 256, 0, stream>>>(h_st, c_st, m_st, out);
}

// Round 13
// 637.527 us; speedup vs baseline: 1.9885x; 1.9885x over previous
//
#include <hip/hip_runtime.h>
#include <hip/hip_bf16.h>

typedef __hip_bfloat16 bf16;
typedef __attribute__((ext_vector_type(8))) short s8v;
typedef __attribute__((ext_vector_type(4))) float f32x4;

#define NN 4096
#define FDIM 16
#define BATCH 4
#define TSTEPS 12

static __device__ __forceinline__ short f2bf(float f) {
  bf16 h = __float2bfloat16(f);
  return *reinterpret_cast<short*>(&h);
}

__device__ __forceinline__ void gload_lds16(const short* g, short* l) {
  __builtin_amdgcn_global_load_lds(
      (const __attribute__((address_space(1))) unsigned int*)g,
      (__attribute__((address_space(3))) unsigned int*)l, 16, 0, 0);
}

// ---------------- adj (f32) -> bf16 copy ----------------
__global__ __launch_bounds__(256) void adj_to_bf16(const float* __restrict__ adjF,
                                                   short* __restrict__ adjB)
{
  size_t i = ((size_t)blockIdx.x * 256 + threadIdx.x) * 8;
  f32x4 u0 = *(const f32x4*)(adjF + i);
  f32x4 u1 = *(const f32x4*)(adjF + i + 4);
  s8v v;
#pragma unroll
  for (int j = 0; j < 4; j++) { v[j] = f2bf(u0[j]); v[4 + j] = f2bf(u1[j]); }
  *(s8v*)(adjB + i) = v;
}

// ---------------- LDS-staged adjacency GEMM ----------------
// out[ks][row][outld] partial = adj[row, k0:k0+kChunk] @ Z^T[col][k]
// Block: 64 rows x 64 cols, 4 waves (16 rows x 64 cols each).
// K-tile 64, double-buffered; A and B staged via global_load_lds (16B),
// XOR-swizzled (16B slot ^= row&7) via pre-swizzled GLOBAL source so the
// linear LDS dest requirement holds; ds_read applies the same XOR.
// BUGFIX r13: A-frag row is wid*16 + r16 (was r16 -> all waves read wave-0's
// rows; masked by adj row-exchangeability into a ~1e-2 deterministic error).
__global__ __launch_bounds__(256) void gemm_tile(
    const short* __restrict__ adjB,  // [4096][4096] bf16 bits
    const short* __restrict__ zt,    // [cols][4096] bf16 bits (B^T layout)
    float* __restrict__ out, int outld, int kChunk)
{
  __shared__ short As[2][4096];      // [buf][row*64 + k] 64x64 bf16
  __shared__ short Bs[2][4096];

  const int tid  = threadIdx.x;
  const int wid  = tid >> 6;
  const int lane = tid & 63;
  const int r16  = lane & 15, g = lane >> 4;
  const int sw   = r16 & 7;
  const int rowBase = blockIdx.x * 64;
  const int colBase = blockIdx.y * 64;
  const int k0 = blockIdx.z * kChunk;

  // staging roles: inst0 covers rows wid*16+0..7, inst1 rows +8..15; lane&7 = 16B slot
  const int srow0 = wid * 16 + (lane >> 3);
  const int srow1 = srow0 + 8;
  const int slot  = lane & 7;
  const short* aS0 = adjB + (size_t)(rowBase + srow0) * NN + k0 + ((slot ^ (srow0 & 7)) << 3);
  const short* aS1 = adjB + (size_t)(rowBase + srow1) * NN + k0 + ((slot ^ (srow1 & 7)) << 3);
  const short* bS0 = zt   + (size_t)(colBase + srow0) * NN + k0 + ((slot ^ (srow0 & 7)) << 3);
  const short* bS1 = zt   + (size_t)(colBase + srow1) * NN + k0 + ((slot ^ (srow1 & 7)) << 3);

#define STAGE(buf, kt) do {                                          \
    gload_lds16(aS0 + (kt), &As[buf][(wid * 16) * 64]);              \
    gload_lds16(aS1 + (kt), &As[buf][(wid * 16 + 8) * 64]);          \
    gload_lds16(bS0 + (kt), &Bs[buf][(wid * 16) * 64]);              \
    gload_lds16(bS1 + (kt), &Bs[buf][(wid * 16 + 8) * 64]);          \
  } while (0)

  f32x4 acc[4];
#pragma unroll
  for (int i = 0; i < 4; i++) acc[i] = (f32x4){0.f, 0.f, 0.f, 0.f};

  STAGE(0, 0);
  __syncthreads();

  const int nt = kChunk >> 6;
  int cur = 0;
  for (int t = 0; t < nt; ++t) {
    if (t + 1 < nt) STAGE(cur ^ 1, (t + 1) << 6);
    const short* Ab = &As[cur][0];
    const short* Bb = &Bs[cur][0];
    // swizzled reads: row r's 16B slot s holds global slot s^(r&7).
    // A rows: wid*16 + r16 (this wave's 16 rows); B rows: cf*16 + r16 (all cols).
    const int ar = wid * 16 + r16;
    s8v a0 = *(const s8v*)&Ab[(ar << 6) + ((g ^ sw) << 3)];
    s8v a1 = *(const s8v*)&Ab[(ar << 6) + (((4 + g) ^ sw) << 3)];
    s8v b0[4], b1[4];
#pragma unroll
    for (int cf = 0; cf < 4; cf++) {
      b0[cf] = *(const s8v*)&Bb[((cf * 16 + r16) << 6) + ((g ^ sw) << 3)];
      b1[cf] = *(const s8v*)&Bb[((cf * 16 + r16) << 6) + (((4 + g) ^ sw) << 3)];
    }
#pragma unroll
    for (int cf = 0; cf < 4; cf++)
      acc[cf] = __builtin_amdgcn_mfma_f32_16x16x32_bf16(a0, b0[cf], acc[cf], 0, 0, 0);
#pragma unroll
    for (int cf = 0; cf < 4; cf++)
      acc[cf] = __builtin_amdgcn_mfma_f32_16x16x32_bf16(a1, b1[cf], acc[cf], 0, 0, 0);
    __syncthreads();   // drains vmcnt (next-tile stage) + lgkmcnt (this tile's ds_reads)
    cur ^= 1;
  }
#undef STAGE

  // C/D layout (m89): col = lane&15, row = (lane>>4)*4 + j
  float* o = out + ((size_t)blockIdx.z * NN + rowBase + wid * 16 + g * 4) * outld + colBase + r16;
#pragma unroll
  for (int cf = 0; cf < 4; cf++)
#pragma unroll
    for (int j = 0; j < 4; j++)
      o[(size_t)j * outld + cf * 16] = acc[cf][j];
}

// ---------------- pack x (f32) into X^T bf16: XT[(b*T+t)*16+f][n] ----------------
__global__ __launch_bounds__(256) void pack_x(const float* __restrict__ x, short* __restrict__ XT)
{
  int idx = blockIdx.x * 256 + threadIdx.x;   // r*4096+n, r=b*T+t
  int r = idx >> 12, n = idx & 4095;
  const float* xp = x + ((size_t)r * NN + n) * FDIM;
#pragma unroll
  for (int q = 0; q < 4; q++) {
    f32x4 u = *(const f32x4*)(xp + q * 4);
#pragma unroll
    for (int j = 0; j < 4; j++)
      XT[(size_t)(r * 16 + q * 4 + j) * NN + n] = f2bf(u[j]);
  }
}

// ---------------- init h=c=m=1 ----------------
__global__ __launch_bounds__(256) void init_state(float* c_st, float* m_st, short* ztA, short* ztB)
{
  int idx = blockIdx.x * 256 + threadIdx.x;   // 0..262143
  int cc = idx >> 12, n = idx & 4095;
  int b = cc >> 4, f = cc & 15;
  short one = f2bf(1.0f);
  ztA[(size_t)cc * NN + n] = one;                        // h0 rows b*16+f
  ztB[(size_t)(b * 32 + 16 + f) * NN + n] = one;         // m0 slot
  c_st[(size_t)(b * NN + n) * FDIM + f] = 1.0f;
  m_st[(size_t)(b * NN + n) * FDIM + f] = 1.0f;
}

// ---------------- step A: gates + LSTM cell update ----------------
__global__ __launch_bounds__(256) void step_a(
    const float* __restrict__ P,    // [16][4096][64]  (adj@h split-K partials)
    const float* __restrict__ AX,   // [4096][768]     (adj@x, all t)
    const float* __restrict__ Wx, const float* __restrict__ bx,
    const float* __restrict__ Wh, const float* __restrict__ bh,
    float* __restrict__ c_st,
    short* __restrict__ ztB,        // write h_mid into rows b*32+f
    int t)
{
  __shared__ float wx[16][64], wh[16][64], bxs[64], bhs[64];
  __shared__ float azxS[16][16], azhS[16][16];
  int tid = threadIdx.x;
#pragma unroll
  for (int i = 0; i < 4; i++) {
    int c = tid + i * 256;
    wx[c >> 6][c & 63] = Wx[c];
    wh[c >> 6][c & 63] = Wh[c];
  }
  if (tid < 64) { bxs[tid] = bx[tid]; bhs[tid] = bh[tid]; }

  int p = tid >> 4, q = tid & 15;
  int pg = blockIdx.x * 16 + p;               // 0..16383 = b*4096+n
  int b = pg >> 12, n = pg & 4095;

  float s = 0.f;
#pragma unroll
  for (int ks = 0; ks < 16; ks++) s += P[(size_t)ks * (NN * 64) + (size_t)n * 64 + b * 16 + q];
  azhS[p][q] = s;
  azxS[p][q] = AX[(size_t)n * 768 + (b * TSTEPS + t) * 16 + q];
  __syncthreads();

  int f = q;
  float azx[16], azh[16];
#pragma unroll
  for (int qq = 0; qq < 16; qq++) { azx[qq] = azxS[p][qq]; azh[qq] = azhS[p][qq]; }

  float fx = bxs[f], ix = bxs[16 + f], cx = bxs[32 + f], ox = bxs[48 + f];
  float fh = bhs[f], ih = bhs[16 + f], ch = bhs[32 + f], oh = bhs[48 + f];
#pragma unroll
  for (int qq = 0; qq < 16; qq++) {
    fx += azx[qq] * wx[qq][f];      ix += azx[qq] * wx[qq][16 + f];
    cx += azx[qq] * wx[qq][32 + f]; ox += azx[qq] * wx[qq][48 + f];
    fh += azh[qq] * wh[qq][f];      ih += azh[qq] * wh[qq][16 + f];
    ch += azh[qq] * wh[qq][32 + f]; oh += azh[qq] * wh[qq][48 + f];
  }
  fx = fmaxf(fx, 0.f); ix = fmaxf(ix, 0.f); cx = fmaxf(cx, 0.f); ox = fmaxf(ox, 0.f);
  fh = fmaxf(fh, 0.f); ih = fmaxf(ih, 0.f); ch = fmaxf(ch, 0.f); oh = fmaxf(oh, 0.f);
  float fg = 1.f / (1.f + __expf(-(fx + fh)));
  float ig = 1.f / (1.f + __expf(-(ix + ih)));
  float og = 1.f / (1.f + __expf(-(ox + oh)));
  float cn = fg * c_st[(size_t)pg * 16 + f] + ig * tanhf(cx + ch);
  float hm = og * tanhf(cn);
  c_st[(size_t)pg * 16 + f] = cn;
  ztB[(size_t)(b * 32 + f) * NN + n] = f2bf(hm);
}

// ---------------- step B: self-attention memory stage ----------------
__global__ __launch_bounds__(256) void step_b(
    const float* __restrict__ P,    // [8][4096][128] (adj@[h_mid|m] partials)
    const float* __restrict__ Wsh, const float* __restrict__ bsh,
    const float* __restrict__ Wsm, const float* __restrict__ bsm,
    float* __restrict__ m_st, float* __restrict__ h_st,
    short* __restrict__ ztA, short* __restrict__ ztB,
    float* __restrict__ outH, int t)
{
  __shared__ float wsh[16][48], wsm[16][48], bshs[48], bsms[48];
  __shared__ float ahS[16][16], amS[16][16];
  int tid = threadIdx.x;
#pragma unroll
  for (int i = 0; i < 3; i++) {
    int c = tid + i * 256;
    wsh[c / 48][c % 48] = Wsh[c];
    wsm[c / 48][c % 48] = Wsm[c];
  }
  if (tid < 48) { bshs[tid] = bsh[tid]; bsms[tid] = bsm[tid]; }

  int p = tid >> 4, q = tid & 15;
  int pg = blockIdx.x * 16 + p;               // b*4096+n
  int b = pg >> 12, n = pg & 4095;

  float s0 = 0.f, s1 = 0.f;
#pragma unroll
  for (int ks = 0; ks < 8; ks++) {
    const float* pp = P + (size_t)ks * (NN * 128) + (size_t)n * 128 + b * 32;
    s0 += pp[q];
    s1 += pp[16 + q];
  }
  ahS[p][q] = s0;
  amS[p][q] = s1;
  __syncthreads();

  int f = q;
  float ah[16], am[16];
#pragma unroll
  for (int qq = 0; qq < 16; qq++) { ah[qq] = ahS[p][qq]; am[qq] = amS[p][qq]; }

  float ih_ = bshs[f], gh_ = bshs[16 + f], oh_ = bshs[32 + f];
  float im_ = bsms[f], gm_ = bsms[16 + f], om_ = bsms[32 + f];
#pragma unroll
  for (int qq = 0; qq < 16; qq++) {
    ih_ += ah[qq] * wsh[qq][f];  gh_ += ah[qq] * wsh[qq][16 + f];  oh_ += ah[qq] * wsh[qq][32 + f];
    im_ += am[qq] * wsm[qq][f];  gm_ += am[qq] * wsm[qq][16 + f];  om_ += am[qq] * wsm[qq][32 + f];
  }
  ih_ = fmaxf(ih_, 0.f); gh_ = fmaxf(gh_, 0.f); oh_ = fmaxf(oh_, 0.f);
  im_ = fmaxf(im_, 0.f); gm_ = fmaxf(gm_, 0.f); om_ = fmaxf(om_, 0.f);
  float i2 = 1.f / (1.f + __expf(-(ih_ + im_)));
  float g2 = 1.f / (1.f + __expf(-(gh_ + gm_)));
  float o2 = 1.f / (1.f + __expf(-(oh_ + om_)));
  float mo = m_st[(size_t)pg * 16 + f];
  float mn = i2 * mo + (1.f - i2) * g2;
  float hn = mn * o2;
  m_st[(size_t)pg * 16 + f] = mn;
  h_st[(size_t)pg * 16 + f] = hn;
  ztA[(size_t)(b * 16 + f) * NN + n] = f2bf(hn);
  ztB[(size_t)(b * 32 + 16 + f) * NN + n] = f2bf(mn);
  outH[((size_t)(b * TSTEPS + t) * NN + n) * FDIM + f] = hn;
}

// ---------------- final: last_h, last_c, last_m (f32 out) ----------------
__global__ __launch_bounds__(256) void finalize(
    const float* __restrict__ h_st, const float* __restrict__ c_st,
    const float* __restrict__ m_st, float* __restrict__ out)
{
  int idx = blockIdx.x * 256 + threadIdx.x;   // 0..262143
  size_t base = (size_t)BATCH * TSTEPS * NN * FDIM;
  out[base + idx]          = h_st[idx];
  out[base + 262144 + idx] = c_st[idx];
  out[base + 524288 + idx] = m_st[idx];
}

extern "C" void kernel_launch(void* const* d_in, const int* in_sizes, int n_in,
                              void* d_out, int out_size, void* d_ws, size_t ws_size,
                              hipStream_t stream)
{
  const float* x    = (const float*)d_in[0];
  const float* adjF = (const float*)d_in[1];
  const float* Wx   = (const float*)d_in[2];
  const float* bx   = (const float*)d_in[3];
  const float* Wh   = (const float*)d_in[4];
  const float* bh   = (const float*)d_in[5];
  const float* Wsh  = (const float*)d_in[6];
  const float* bsh  = (const float*)d_in[7];
  const float* Wsm  = (const float*)d_in[8];
  const float* bsm  = (const float*)d_in[9];
  float* out = (float*)d_out;

  char* ws = (char*)d_ws;
  float* AX   = (float*)ws;                    // 4096*768*4    = 12,582,912
  float* P    = (float*)(ws + 12582912);       // 16*4096*64*4  = 16,777,216 (== 8*4096*128*4)
  short* XT   = (short*)(ws + 29360128);       // 768*4096*2    =  6,291,456
  short* ztA  = (short*)(ws + 35651584);       // 64*4096*2     =    524,288
  short* ztB  = (short*)(ws + 36175872);       // 128*4096*2    =  1,048,576
  float* c_st = (float*)(ws + 37224448);       // 1,048,576 each
  float* m_st = (float*)(ws + 38273024);
  float* h_st = (float*)(ws + 39321600);
  short* adjB = (short*)(ws + 40370176);       // 4096*4096*2   = 33,554,432

  init_state<<<1024, 256, 0, stream>>>(c_st, m_st, ztA, ztB);
  pack_x<<<768, 256, 0, stream>>>(x, XT);
  adj_to_bf16<<<8192, 256, 0, stream>>>(adjF, adjB);

  // adj @ x for all (b,t): 768 cols, 12 col-tiles, full K
  gemm_tile<<<dim3(64, 12, 1), 256, 0, stream>>>(adjB, XT, AX, 768, 4096);

  for (int t = 0; t < TSTEPS; t++) {
    // adj @ h : 64 cols, split-K=16 -> 1024 blocks (4/CU)
    gemm_tile<<<dim3(64, 1, 16), 256, 0, stream>>>(adjB, ztA, P, 64, 256);
    step_a<<<1024, 256, 0, stream>>>(P, AX, Wx, bx, Wh, bh, c_st, ztB, t);
    // adj @ [h_mid | m] : 128 cols, 2 col-tiles x split-K=8 -> 1024 blocks
    gemm_tile<<<dim3(64, 2, 8), 256, 0, stream>>>(adjB, ztB, P, 128, 512);
    step_b<<<1024, 256, 0, stream>>>(P, Wsh, bsh, Wsm, bsm, m_st, h_st, ztA, ztB, out, t);
  }
  finalize<<<1024, 256, 0, stream>>>(h_st, c_st, m_st, out);
}